// Round 1
// baseline (10165.969 us; speedup 1.0000x reference)
//
#include <hip/hip_runtime.h>
#include <hip/hip_fp16.h>

#define H 1024
#define B 512
#define T 512
#define NC 10

typedef _Float16 f16x8 __attribute__((ext_vector_type(8)));
typedef _Float16 f16x4 __attribute__((ext_vector_type(4)));
typedef float    f32x4 __attribute__((ext_vector_type(4)));

// ---- convert W_hh f32 -> f16 (row-major [H][H]) ----
__global__ void convert_w(const float* __restrict__ w, _Float16* __restrict__ o) {
    int i = (blockIdx.x * 256 + threadIdx.x) * 4;
    float4 v = *(const float4*)(w + i);
    f16x4 r;
    r[0] = (_Float16)v.x; r[1] = (_Float16)v.y;
    r[2] = (_Float16)v.z; r[3] = (_Float16)v.w;
    *(f16x4*)(o + i) = r;
}

// ---- one RNN timestep: hout[n][m] = tanh( sum_k W[m][k]*hin[n][k] + Whx[m]*x[n][t] + bh[n] ) ----
// W   : f16 [H][H] row-major (A operand, rows = m, k-contiguous)
// hin : f16 [B][H] row-major (h transposed; B operand, rows = n(batch), k-contiguous)
// grid: (16 M-tiles, 8 N-tiles), block 256 = 4 waves; WG tile 64x64, wave tile 32x32
__global__ void rnn_step(const _Float16* __restrict__ W,
                         const _Float16* __restrict__ hin,
                         _Float16* __restrict__ hout,
                         const float* __restrict__ Whx,
                         const float* __restrict__ x,
                         const float* __restrict__ bh,
                         int t) {
    const int wave = threadIdx.x >> 6;
    const int lane = threadIdx.x & 63;
    const int lm = lane & 15;   // row/col within 16x16 fragment
    const int kg = lane >> 4;   // k-group 0..3 (8 f16 each)

    const int mbase = blockIdx.x * 64 + (wave & 1) * 32;
    const int nbase = blockIdx.y * 64 + (wave >> 1) * 32;

    const _Float16* A0 = W   + (size_t)(mbase + lm) * H + kg * 8;
    const _Float16* A1 = A0 + 16 * H;
    const _Float16* B0 = hin + (size_t)(nbase + lm) * H + kg * 8;
    const _Float16* B1 = B0 + 16 * H;

    f32x4 acc00 = 0.f, acc01 = 0.f, acc10 = 0.f, acc11 = 0.f;

    #pragma unroll 4
    for (int kk = 0; kk < H; kk += 32) {
        f16x8 a0 = *(const f16x8*)(A0 + kk);
        f16x8 a1 = *(const f16x8*)(A1 + kk);
        f16x8 b0 = *(const f16x8*)(B0 + kk);
        f16x8 b1 = *(const f16x8*)(B1 + kk);
        acc00 = __builtin_amdgcn_mfma_f32_16x16x32_f16(a0, b0, acc00, 0, 0, 0);
        acc01 = __builtin_amdgcn_mfma_f32_16x16x32_f16(a0, b1, acc01, 0, 0, 0);
        acc10 = __builtin_amdgcn_mfma_f32_16x16x32_f16(a1, b0, acc10, 0, 0, 0);
        acc11 = __builtin_amdgcn_mfma_f32_16x16x32_f16(a1, b1, acc11, 0, 0, 0);
    }

    // epilogue: D[row m][col n], m = mbase + fm*16 + kg*4 + r, n = nbase + fn*16 + lm
    f32x4 accs[2][2] = { {acc00, acc01}, {acc10, acc11} };
    #pragma unroll
    for (int fn = 0; fn < 2; ++fn) {
        const int n  = nbase + fn * 16 + lm;
        const float xn = x[(size_t)n * T + t];
        const float bn = bh[n];
        #pragma unroll
        for (int fm = 0; fm < 2; ++fm) {
            const int mb = mbase + fm * 16 + kg * 4;
            f16x4 sv;
            #pragma unroll
            for (int r = 0; r < 4; ++r) {
                float pre = accs[fm][fn][r] + Whx[mb + r] * xn + bn;
                float e = __expf(2.0f * pre);
                float th = 1.0f - 2.0f / (e + 1.0f);
                sv[r] = (_Float16)th;
            }
            *(f16x4*)(hout + (size_t)n * H + mb) = sv;
        }
    }
}

// ---- final projection: out[b][c] = sum_h Wph[c][h] * hT[b][h] + bp[b] ----
__global__ void proj_kernel(const _Float16* __restrict__ hT,
                            const float* __restrict__ Wph,
                            const float* __restrict__ bp,
                            float* __restrict__ out) {
    const int b = blockIdx.x;
    const int lane = threadIdx.x;  // 64
    float partial[NC];
    #pragma unroll
    for (int c = 0; c < NC; ++c) partial[c] = 0.f;
    for (int h = lane; h < H; h += 64) {
        float hv = (float)hT[(size_t)b * H + h];
        #pragma unroll
        for (int c = 0; c < NC; ++c) partial[c] += Wph[(size_t)c * H + h] * hv;
    }
    #pragma unroll
    for (int c = 0; c < NC; ++c) {
        float v = partial[c];
        #pragma unroll
        for (int off = 32; off; off >>= 1) v += __shfl_down(v, off);
        if (lane == 0) out[(size_t)b * NC + c] = v + bp[b];
    }
}

extern "C" void kernel_launch(void* const* d_in, const int* in_sizes, int n_in,
                              void* d_out, int out_size, void* d_ws, size_t ws_size,
                              hipStream_t stream) {
    const float* x   = (const float*)d_in[0];
    const float* Whx = (const float*)d_in[1];
    const float* Whh = (const float*)d_in[2];
    const float* Wph = (const float*)d_in[3];
    const float* bh  = (const float*)d_in[4];
    const float* bp  = (const float*)d_in[5];
    float* out = (float*)d_out;

    char* ws = (char*)d_ws;
    _Float16* Wf = (_Float16*)ws;                                     // 2 MB
    _Float16* h0 = (_Float16*)(ws + (size_t)H * H * 2);               // 1 MB
    _Float16* h1 = (_Float16*)(ws + (size_t)H * H * 2 + (size_t)B * H * 2);

    convert_w<<<(H * H / 4) / 256, 256, 0, stream>>>(Whh, Wf);
    hipMemsetAsync(h0, 0, (size_t)B * H * 2, stream);

    const _Float16* hin = h0;
    _Float16* hout = h1;
    for (int t = 0; t < T; ++t) {
        rnn_step<<<dim3(16, 8), 256, 0, stream>>>(Wf, hin, hout, Whx, x, bh, t);
        _Float16* tmp = (_Float16*)hin;
        hin = hout;
        hout = tmp;
    }

    proj_kernel<<<B, 64, 0, stream>>>(hin, Wph, bp, out);
}